// Round 11
// baseline (42.357 us; speedup 1.0000x reference)
//
#include <hip/hip_runtime.h>

// SSIM loss, N=64 images, 1 ch, 384x384 f32, 7x7 box, VALID -> 378x378. out = -mean(S).
//
// R11: dual-stream ILP. Grid unchanged (27 bands x 64 imgs = 1728 one-wave
// blocks; R6/R7 proved more waves = more prologue overhead = slower). Each
// wave processes its 14-row band as TWO independent 7-row streams (A: rows
// r0..r0+6, B: r0+7..r0+13) interleaved in one instruction stream, so when
// one stream stalls (vmcnt / lgkm / VALU dep) the other issues. To fit 2x
// state in 256 VGPR, the 84-reg raw-row history is replaced by reloading the
// old row from cache with a 2-DEEP old-row prefetch pipe (R6 failed with
// 1-step cover; here load->use distance = 2 full dual-stream bodies).
//  - lane owns cols 6l..6l+5 (64*6=384); horizontal 7-tap via prefix/suffix
//    + 6 depth-1 shuffles per moment (R10-verified math)
//  - t34 merge (one window sum of sxx+syy)
//  - rolled 7-step loop: no history slots -> pure register rotation
//  - two-kernel deterministic reduction

constexpr int IND   = 384;
constexpr int OUTD  = 378;
constexpr int RB    = 14;            // output rows per band (2 streams x 7)
constexpr int BANDS = OUTD / RB;     // 27
constexpr int CPL   = 6;             // cols per lane

using f32x2 = __attribute__((ext_vector_type(2))) float;

__global__ __launch_bounds__(64, 2)
void ssim_band(const float* __restrict__ X, const float* __restrict__ Y,
               const float* __restrict__ MX, float* __restrict__ blocksum)
{
    const int band = blockIdx.x;
    const int n    = blockIdx.y;
    const int lane = threadIdx.x;
    const int c0   = lane * CPL;
    const int r0   = band * RB;      // r0 <= 364

    const float* __restrict__ Xp = X + (size_t)n * (IND * IND) + c0;
    const float* __restrict__ Yp = Y + (size_t)n * (IND * IND) + c0;

#define LOADROW(DX, DY, R) {                                                  \
    const float* _px = Xp + (size_t)(R) * IND;                                \
    const float* _py = Yp + (size_t)(R) * IND;                                \
    f32x2 _a = *(const f32x2*)_px;   f32x2 _b = *(const f32x2*)(_px + 2);     \
    f32x2 _c = *(const f32x2*)(_px + 4);                                      \
    f32x2 _d = *(const f32x2*)_py;   f32x2 _e = *(const f32x2*)(_py + 2);     \
    f32x2 _f = *(const f32x2*)(_py + 4);                                      \
    DX[0]=_a.x; DX[1]=_a.y; DX[2]=_b.x; DX[3]=_b.y; DX[4]=_c.x; DX[5]=_c.y;   \
    DY[0]=_d.x; DY[1]=_d.y; DY[2]=_e.x; DY[3]=_e.y; DY[4]=_f.x; DY[5]=_f.y; }

#define ACCROW(SX,SY,SXX,SYY,SXY, RX,RY)                                      \
    _Pragma("unroll")                                                         \
    for (int c = 0; c < CPL; ++c) {                                           \
        float x = RX[c], y = RY[c];                                           \
        SX[c] += x;  SY[c] += y;                                              \
        SXX[c] = fmaf(x, x, SXX[c]);                                          \
        SYY[c] = fmaf(y, y, SYY[c]);                                          \
        SXY[c] = fmaf(x, y, SXY[c]); }

#define SUBROW(SX,SY,SXX,SYY,SXY, RX,RY)                                      \
    _Pragma("unroll")                                                         \
    for (int c = 0; c < CPL; ++c) {                                           \
        float x = RX[c], y = RY[c];                                           \
        SX[c] -= x;  SY[c] -= y;                                              \
        SXX[c] = fmaf(-x, x, SXX[c]);                                         \
        SYY[c] = fmaf(-y, y, SYY[c]);                                         \
        SXY[c] = fmaf(-x, y, SXY[c]); }

#define COPYROW(DX,DY, SX,SY)                                                 \
    _Pragma("unroll")                                                         \
    for (int c = 0; c < CPL; ++c) { DX[c] = SX[c]; DY[c] = SY[c]; }

    // Prefix/suffix horizontal window (R10-verified):
    //   p_k = S[0]+..+S[k-1];  NP[j] = shfl_down(p_{j+1}, 1)
    //   CS[j] = S[j]+..+S[5];  O[j]  = CS[j] + NP[j]
#define PHASE_A(S, NP, CS) {                                                  \
    float _p1 = S[0];                                                         \
    float _p2 = _p1 + S[1];                                                   \
    float _p3 = _p2 + S[2];                                                   \
    float _p4 = _p3 + S[3];                                                   \
    float _p5 = _p4 + S[4];                                                   \
    float _p6 = _p5 + S[5];                                                   \
    NP[0] = __shfl_down(_p1, 1);                                              \
    NP[1] = __shfl_down(_p2, 1);                                              \
    NP[2] = __shfl_down(_p3, 1);                                              \
    NP[3] = __shfl_down(_p4, 1);                                              \
    NP[4] = __shfl_down(_p5, 1);                                              \
    NP[5] = __shfl_down(_p6, 1);                                              \
    CS[5] = S[5];                                                             \
    CS[4] = S[4] + S[5];                                                      \
    CS[3] = S[3] + CS[4];                                                     \
    CS[2] = S[2] + CS[3];                                                     \
    CS[1] = S[1] + CS[2];                                                     \
    CS[0] = _p6; }

    // ---- stream state ----
    float sxA[CPL]={}, syA[CPL]={}, sxxA[CPL]={}, syyA[CPL]={}, sxyA[CPL]={};
    float naxA[CPL], nayA[CPL], nbxA[CPL], nbyA[CPL];   // new-row pipe (2-deep)
    float oaxA[CPL], oayA[CPL], obxA[CPL], obyA[CPL];   // old-row pipe (2-deep)
    float sxB[CPL]={}, syB[CPL]={}, sxxB[CPL]={}, syyB[CPL]={}, sxyB[CPL]={};
    float naxB[CPL], nayB[CPL], nbxB[CPL], nbyB[CPL];
    float oaxB[CPL], oayB[CPL], obxB[CPL], obyB[CPL];

    // ---- prologue: batch-issue the 8 persistent row loads first ----
    LOADROW(oaxA, oayA, r0 + 0)       // old rows r0, r0+1 (consumed steps 0,1)
    LOADROW(obxA, obyA, r0 + 1)
    LOADROW(naxA, nayA, r0 + 6)       // new rows r0+6, r0+7 (steps 0,1)
    LOADROW(nbxA, nbyA, r0 + 7)
    LOADROW(oaxB, oayB, r0 + 7)
    LOADROW(obxB, obyB, r0 + 8)
    LOADROW(naxB, nayB, r0 + 13)
    LOADROW(nbxB, nbyB, r0 + 14)

    // stream A init: sums over rows r0..r0+5
    ACCROW(sxA,syA,sxxA,syyA,sxyA, oaxA,oayA)
    ACCROW(sxA,syA,sxxA,syyA,sxyA, obxA,obyA)
#pragma unroll
    for (int k = 2; k < 6; ++k) {
        float tx[CPL], ty[CPL];
        LOADROW(tx, ty, r0 + k)
        ACCROW(sxA,syA,sxxA,syyA,sxyA, tx,ty)
    }
    // stream B init: sums over rows r0+7..r0+12
    ACCROW(sxB,syB,sxxB,syyB,sxyB, oaxB,oayB)
    ACCROW(sxB,syB,sxxB,syyB,sxyB, obxB,obyB)
#pragma unroll
    for (int k = 9; k < 13; ++k) {
        float tx[CPL], ty[CPL];
        LOADROW(tx, ty, r0 + k)
        ACCROW(sxB,syB,sxxB,syyB,sxyB, tx,ty)
    }

    const float m   = MX[n];
    const float c1  = (0.01f * m) * (0.01f * m);
    const float c2  = (0.03f * m) * (0.03f * m);
    const float k1  = 2401.0f * c1;      // 49^2 * C1
    const float k2  = 2401.0f * c2;
    const float cn  = 49.0f / 48.0f;
    const float cn2 = 2.0f * cn;

    float partial = 0.f;

    // One stream's full step: add new -> shuffles -> sub old + rotate +
    // prefetch (2 ahead) -> formula. OLDR/NEWR are the rows loaded INTO the
    // 2-deep pipes (consumed two steps later).
#define STREAMSTEP(sx,sy,sxx,syy,sxy, nax,nay,nbx,nby, oax,oay,obx,oby, OLDR, NEWR) \
    {                                                                         \
        ACCROW(sx,sy,sxx,syy,sxy, nax,nay)                                    \
        float u[CPL];                                                         \
        _Pragma("unroll")                                                     \
        for (int c = 0; c < CPL; ++c) u[c] = sxx[c] + syy[c];                 \
        float np1[CPL], np2[CPL], np5[CPL], np34[CPL];                        \
        float cs1[CPL], cs2[CPL], cs5[CPL], cs34[CPL];                        \
        PHASE_A(sx,  np1,  cs1)                                               \
        PHASE_A(sy,  np2,  cs2)                                               \
        PHASE_A(sxy, np5,  cs5)                                               \
        PHASE_A(u,   np34, cs34)                                              \
        SUBROW(sx,sy,sxx,syy,sxy, oax,oay)                                    \
        COPYROW(oax,oay, obx,oby)                                             \
        COPYROW(nax,nay, nbx,nby)                                             \
        { int _r = (OLDR); LOADROW(obx,oby, _r) }                             \
        { int _r = (NEWR); if (_r > IND - 1) _r = IND - 1;                    \
          LOADROW(nbx,nby, _r) }                                              \
        if (lane < 63) {                                                      \
            _Pragma("unroll")                                                 \
            for (int c = 0; c < CPL; ++c) {                                   \
                float t1  = cs1[c]  + np1[c];                                 \
                float t2  = cs2[c]  + np2[c];                                 \
                float t5  = cs5[c]  + np5[c];                                 \
                float t34 = cs34[c] + np34[c];                                \
                float pxy = t1 * t2;                                          \
                float ss  = fmaf(t1, t1, t2 * t2);                            \
                float A1  = fmaf(2.f, pxy, k1);                               \
                float B1  = ss + k1;                                          \
                float A2  = fmaf(cn2, fmaf(49.f, t5, -pxy), k2);              \
                float B2  = fmaf(cn,  fmaf(49.f, t34, -ss), k2);              \
                partial += __fdividef(A1 * A2, B1 * B2);                      \
            }                                                                 \
        }                                                                     \
    }

#pragma unroll 1                       // rolled: ~4 KB body, I$-resident
    for (int i = 0; i < 7; ++i) {
        // stream A: output row r0+i      (window rows r0+i .. r0+i+6)
        STREAMSTEP(sxA,syA,sxxA,syyA,sxyA, naxA,nayA,nbxA,nbyA,
                   oaxA,oayA,obxA,obyA, r0 + i + 2, r0 + i + 8)
        // stream B: output row r0+7+i    (window rows r0+7+i .. r0+13+i)
        STREAMSTEP(sxB,syB,sxxB,syyB,sxyB, naxB,nayB,nbxB,nbyB,
                   oaxB,oayB,obxB,obyB, r0 + i + 9, r0 + i + 15)
    }
#undef STREAMSTEP
#undef PHASE_A
#undef COPYROW
#undef SUBROW
#undef ACCROW
#undef LOADROW

    // ---- wave reduction (deterministic) ----
#pragma unroll
    for (int off = 32; off; off >>= 1) partial += __shfl_down(partial, off);
    if (lane == 0) blocksum[(size_t)n * BANDS + band] = partial;
}

__global__ __launch_bounds__(256)
void ssim_reduce(const float* __restrict__ blocksum, float* __restrict__ out,
                 int nblocks, float inv_npix)
{
    const int tid = threadIdx.x;
    float s = 0.f;
    for (int i = tid; i < nblocks; i += 256) s += blocksum[i];
#pragma unroll
    for (int off = 32; off; off >>= 1) s += __shfl_down(s, off);
    __shared__ float ws[4];
    if ((tid & 63) == 0) ws[tid >> 6] = s;
    __syncthreads();
    if (tid == 0) out[0] = -(ws[0] + ws[1] + ws[2] + ws[3]) * inv_npix;
}

extern "C" void kernel_launch(void* const* d_in, const int* in_sizes, int n_in,
                              void* d_out, int out_size, void* d_ws, size_t ws_size,
                              hipStream_t stream)
{
    const float* X  = (const float*)d_in[0];
    const float* Y  = (const float*)d_in[1];
    // d_in[2] = norm (unused by reference), d_in[4] = w (ones/49, baked in)
    const float* MX = (const float*)d_in[3];

    const int N       = in_sizes[3];             // 64
    const int nblocks = N * BANDS;               // 1728

    float* bs = (float*)d_ws;

    dim3 grid(BANDS, N);
    ssim_band<<<grid, 64, 0, stream>>>(X, Y, MX, bs);

    const float inv_npix = 1.0f / ((float)N * OUTD * OUTD);
    ssim_reduce<<<1, 256, 0, stream>>>(bs, (float*)d_out, nblocks, inv_npix);
}

// Round 12
// 31.782 us; speedup vs baseline: 1.3327x; 1.3327x over previous
//
#include <hip/hip_runtime.h>

// SSIM loss, N=64 images, 1 ch, 384x384 f32, 7x7 box, VALID -> 378x378. out = -mean(S).
//
// R12 = R8 (28.45us best) + 4-deep new-row prefetch pipe.
// Evidence chain: R11's dual-stream doubled achieved BW (2646 vs ~1200 GB/s)
// proving the kernel is memory-CONCURRENCY-bound, but paid 2x bytes for the
// old-row reloads. R12 keeps R8's register history (minimal bytes) and gets
// the concurrency by holding 4 prefetched rows in flight instead of 2
// (pa/pb/pc/pd, load->consume distance ~3.5 steps). Step reordered so the
// load issues before the formula tail. Everything else R8-verbatim:
//  - lane owns cols 6l..6l+5 (64*6=384), RB=14, 27x64=1728 one-wave blocks
//  - 7-deep raw register history, statically indexed (7-step inner unroll)
//  - immediate-consume sliding HSUM (R10 proved batching is perf-neutral)
//  - t34 merge; outer kk loop rolled (I$); two-kernel deterministic reduction

constexpr int IND   = 384;
constexpr int OUTD  = 378;
constexpr int RB    = 14;            // output rows per band
constexpr int BANDS = OUTD / RB;     // 27
constexpr int CPL   = 6;             // cols per lane

using f32x2 = __attribute__((ext_vector_type(2))) float;

__global__ __launch_bounds__(64, 2)
void ssim_band(const float* __restrict__ X, const float* __restrict__ Y,
               const float* __restrict__ MX, float* __restrict__ blocksum)
{
    const int band = blockIdx.x;
    const int n    = blockIdx.y;
    const int lane = threadIdx.x;
    const int c0   = lane * CPL;
    const int r0   = band * RB;      // r0 <= 364

    const float* __restrict__ Xp = X + (size_t)n * (IND * IND) + c0;
    const float* __restrict__ Yp = Y + (size_t)n * (IND * IND) + c0;

    float hx[7][CPL], hy[7][CPL];                  // raw 7-row history
    float sx[CPL]  = {}, sy[CPL]  = {};
    float sxx[CPL] = {}, syy[CPL] = {}, sxy[CPL] = {};

#define LOADROW(DX, DY, R) {                                                  \
    const float* _px = Xp + (size_t)(R) * IND;                                \
    const float* _py = Yp + (size_t)(R) * IND;                                \
    f32x2 _a = *(const f32x2*)_px;                                            \
    f32x2 _b = *(const f32x2*)(_px + 2);                                      \
    f32x2 _c = *(const f32x2*)(_px + 4);                                      \
    f32x2 _d = *(const f32x2*)_py;                                            \
    f32x2 _e = *(const f32x2*)(_py + 2);                                      \
    f32x2 _f = *(const f32x2*)(_py + 4);                                      \
    DX[0]=_a.x; DX[1]=_a.y; DX[2]=_b.x; DX[3]=_b.y; DX[4]=_c.x; DX[5]=_c.y;   \
    DY[0]=_d.x; DY[1]=_d.y; DY[2]=_e.x; DY[3]=_e.y; DY[4]=_f.x; DY[5]=_f.y; }

    // ---- prologue: 11 row-loads issued back-to-back (66 dwordx2 in flight):
    //      history rows r0..r0+6, pipe rows r0+7..r0+10 ----
#pragma unroll
    for (int k = 0; k < 7; ++k) LOADROW(hx[k], hy[k], r0 + k)

    float pax[CPL], pay[CPL], pbx[CPL], pby[CPL];
    float pcx[CPL], pcy[CPL], pdx[CPL], pdy[CPL];
    LOADROW(pax, pay, r0 + 7)
    LOADROW(pbx, pby, r0 + 8)
    LOADROW(pcx, pcy, r0 + 9)
    LOADROW(pdx, pdy, r0 + 10)

#pragma unroll
    for (int k = 0; k < 7; ++k)
#pragma unroll
        for (int c = 0; c < CPL; ++c) {
            float x = hx[k][c], y = hy[k][c];
            sx[c] += x;  sy[c] += y;
            sxx[c] = fmaf(x, x, sxx[c]);
            syy[c] = fmaf(y, y, syy[c]);
            sxy[c] = fmaf(x, y, sxy[c]);
        }

    const float m   = MX[n];
    const float c1  = (0.01f * m) * (0.01f * m);
    const float c2  = (0.03f * m) * (0.03f * m);
    const float k1  = 2401.0f * c1;      // 49^2 * C1
    const float k2  = 2401.0f * c2;
    const float cn  = 49.0f / 48.0f;
    const float cn2 = 2.0f * cn;

    // horizontal sliding sum: O[i] = sum over window cols (6l+i .. 6l+i+6)
#define HSUM(S, O) {                                                          \
    float _n0 = __shfl_down(S[0], 1), _n1 = __shfl_down(S[1], 1);             \
    float _n2 = __shfl_down(S[2], 1), _n3 = __shfl_down(S[3], 1);             \
    float _n4 = __shfl_down(S[4], 1), _n5 = __shfl_down(S[5], 1);             \
    float _t  = ((S[0]+S[1]) + (S[2]+S[3])) + (S[4]+S[5]);                    \
    O[0] = _t   + _n0;                                                        \
    O[1] = O[0] - S[0] + _n1;                                                 \
    O[2] = O[1] - S[1] + _n2;                                                 \
    O[3] = O[2] - S[2] + _n3;                                                 \
    O[4] = O[3] - S[3] + _n4;                                                 \
    O[5] = O[4] - S[4] + _n5; }

    float partial = 0.f;

    // Invariant at step s = r0+7kk+i: sums hold rows s..s+6;
    // pax=s+7, pbx=s+8, pcx=s+9, pdx=s+10.
#pragma unroll 1                       // keep the 7-step body I$-resident
    for (int kk = 0; kk < RB / 7; ++kk) {
#pragma unroll
        for (int i = 0; i < 7; ++i) {
            // ---- 1. capture horizontal 7-tap window sums for output row s ----
            float t1[CPL], t2[CPL], t34[CPL], t5[CPL], u[CPL];
            HSUM(sx,  t1) HSUM(sy,  t2) HSUM(sxy, t5)
#pragma unroll
            for (int c = 0; c < CPL; ++c) u[c] = sxx[c] + syy[c];
            HSUM(u, t34)

            // ---- 2. slide (-row s, +row s+7), rotate pipe, issue load ----
#pragma unroll
            for (int c = 0; c < CPL; ++c) {
                float nx = pax[c], ny = pay[c];
                float ox = hx[i][c], oy = hy[i][c];
                sx[c] += nx - ox;
                sy[c] += ny - oy;
                sxx[c] = fmaf(nx, nx, fmaf(-ox, ox, sxx[c]));
                syy[c] = fmaf(ny, ny, fmaf(-oy, oy, syy[c]));
                sxy[c] = fmaf(nx, ny, fmaf(-ox, oy, sxy[c]));
                hx[i][c] = nx;   hy[i][c] = ny;
                pax[c] = pbx[c]; pay[c] = pby[c];
                pbx[c] = pcx[c]; pby[c] = pcy[c];
                pcx[c] = pdx[c]; pcy[c] = pdy[c];
            }
            {
                int nr = r0 + 7 * kk + i + 11;     // 4 rows ahead
                if (nr > IND - 1) nr = IND - 1;    // tail: clamped, never consumed
                LOADROW(pdx, pdy, nr)
            }

            // ---- 3. SSIM formula (49^4-scaled, q-invariant) ----
            if (lane < 63) {
#pragma unroll
                for (int c = 0; c < CPL; ++c) {
                    float pxy = t1[c] * t2[c];
                    float ss  = fmaf(t1[c], t1[c], t2[c] * t2[c]);
                    float A1  = fmaf(2.f, pxy, k1);
                    float B1  = ss + k1;
                    float A2  = fmaf(cn2, fmaf(49.f, t5[c], -pxy), k2);
                    float B2  = fmaf(cn, fmaf(49.f, t34[c], -ss), k2);
                    partial += __fdividef(A1 * A2, B1 * B2);
                }
            }
        }
    }
#undef HSUM
#undef LOADROW

    // ---- wave reduction (deterministic) ----
#pragma unroll
    for (int off = 32; off; off >>= 1) partial += __shfl_down(partial, off);
    if (lane == 0) blocksum[(size_t)n * BANDS + band] = partial;
}

__global__ __launch_bounds__(256)
void ssim_reduce(const float* __restrict__ blocksum, float* __restrict__ out,
                 int nblocks, float inv_npix)
{
    const int tid = threadIdx.x;
    float s = 0.f;
    for (int i = tid; i < nblocks; i += 256) s += blocksum[i];
#pragma unroll
    for (int off = 32; off; off >>= 1) s += __shfl_down(s, off);
    __shared__ float ws[4];
    if ((tid & 63) == 0) ws[tid >> 6] = s;
    __syncthreads();
    if (tid == 0) out[0] = -(ws[0] + ws[1] + ws[2] + ws[3]) * inv_npix;
}

extern "C" void kernel_launch(void* const* d_in, const int* in_sizes, int n_in,
                              void* d_out, int out_size, void* d_ws, size_t ws_size,
                              hipStream_t stream)
{
    const float* X  = (const float*)d_in[0];
    const float* Y  = (const float*)d_in[1];
    // d_in[2] = norm (unused by reference), d_in[4] = w (ones/49, baked in)
    const float* MX = (const float*)d_in[3];

    const int N       = in_sizes[3];             // 64
    const int nblocks = N * BANDS;               // 1728

    float* bs = (float*)d_ws;

    dim3 grid(BANDS, N);
    ssim_band<<<grid, 64, 0, stream>>>(X, Y, MX, bs);

    const float inv_npix = 1.0f / ((float)N * OUTD * OUTD);
    ssim_reduce<<<1, 256, 0, stream>>>(bs, (float*)d_out, nblocks, inv_npix);
}